// Round 2
// baseline (5658.524 us; speedup 1.0000x reference)
//
#include <hip/hip_runtime.h>

constexpr int N = 50000;    // nodes
constexpr int E = 800000;   // edges
// layer widths: 128 -> 256 -> 256

// ---------------- degree / normalization ----------------
__global__ __launch_bounds__(256) void deg_kernel(const int* __restrict__ dst,
                                                  float* __restrict__ deg) {
    int e = blockIdx.x * 256 + threadIdx.x;
    if (e < E) atomicAdd(&deg[dst[e]], 1.0f);
}

__global__ __launch_bounds__(256) void dinv_kernel(float* __restrict__ deg) {
    int v = blockIdx.x * 256 + threadIdx.x;
    if (v < N) deg[v] = rsqrtf(deg[v] + 1.0f);   // +1 = self loop; always > 0
}

// ---------------- GEMM with dinv row-scale epilogue ----------------
// out[m, c] = dinv[m] * sum_k A[m,k] * W[k,c];   A: [N,K], W: [K,256], out: [N,256]
template <int K>
__global__ __launch_bounds__(256) void gemm_scale_kernel(
    const float* __restrict__ A, const float* __restrict__ W,
    const float* __restrict__ dinv, float* __restrict__ out) {
    constexpr int BM = 64, BN = 64, BK = 32, CN = 256;
    __shared__ __align__(16) float As[BK][BM + 4];  // stored transposed: As[k][m]
    __shared__ __align__(16) float Bs[BK][BN + 4];

    const int bm = blockIdx.x * BM;
    const int bn = blockIdx.y * BN;
    const int tid = threadIdx.x;
    const int tx = tid & 15;   // output col group
    const int ty = tid >> 4;   // output row group

    float acc[4][4] = {};

    for (int k0 = 0; k0 < K; k0 += BK) {
        // --- load A tile 64x32 (float4, coalesced), store transposed ---
        {
            int kk = (tid & 7) * 4;      // k offset within tile
            int r0 = tid >> 3;           // 0..31
#pragma unroll
            for (int rr = 0; rr < 2; ++rr) {
                int r = r0 + rr * 32;
                int m = bm + r;
                float4 v = make_float4(0.f, 0.f, 0.f, 0.f);
                if (m < N) v = *(const float4*)&A[(size_t)m * K + k0 + kk];
                As[kk + 0][r] = v.x;
                As[kk + 1][r] = v.y;
                As[kk + 2][r] = v.z;
                As[kk + 3][r] = v.w;
            }
        }
        // --- load B tile 32x64 (float4, coalesced) ---
        {
            int c4 = (tid & 15) * 4;
            int r0 = tid >> 4;           // 0..15
#pragma unroll
            for (int rr = 0; rr < 2; ++rr) {
                int r = r0 + rr * 16;
                float4 v = *(const float4*)&W[(size_t)(k0 + r) * CN + bn + c4];
                *(float4*)&Bs[r][c4] = v;
            }
        }
        __syncthreads();

#pragma unroll
        for (int k = 0; k < BK; ++k) {
            float4 a4 = *(const float4*)&As[k][ty * 4];
            float4 b4 = *(const float4*)&Bs[k][tx * 4];
            float av[4] = {a4.x, a4.y, a4.z, a4.w};
            float bv[4] = {b4.x, b4.y, b4.z, b4.w};
#pragma unroll
            for (int i = 0; i < 4; ++i)
#pragma unroll
                for (int j = 0; j < 4; ++j) acc[i][j] = fmaf(av[i], bv[j], acc[i][j]);
        }
        __syncthreads();
    }

#pragma unroll
    for (int i = 0; i < 4; ++i) {
        int m = bm + ty * 4 + i;
        if (m < N) {
            float dv = dinv[m];
            float4 r;
            r.x = acc[i][0] * dv;
            r.y = acc[i][1] * dv;
            r.z = acc[i][2] * dv;
            r.w = acc[i][3] * dv;
            *(float4*)&out[(size_t)m * CN + bn + tx * 4] = r;
        }
    }
}

// ---------------- edge scatter-add: agg[dst] += g[src]  (256 ch) ----------------
__global__ __launch_bounds__(256) void scatter_kernel(
    const int* __restrict__ src, const int* __restrict__ dst,
    const float4* __restrict__ g, float4* __restrict__ agg) {
    int t = blockIdx.x * 256 + threadIdx.x;
    int e = t >> 6;                // 64 threads (one wave) per edge
    if (e >= E) return;
    int c4 = t & 63;               // float4 index -> channels c4*4..c4*4+3
    int s = src[e], d = dst[e];
    float4 v = g[(size_t)s * 64 + c4];
    float* ap = (float*)(agg + (size_t)d * 64 + c4);
    atomicAdd(ap + 0, v.x);
    atomicAdd(ap + 1, v.y);
    atomicAdd(ap + 2, v.z);
    atomicAdd(ap + 3, v.w);
}

// ---------------- finalize: out = [relu](dinv[v]*(agg+g) + bias) ----------------
// NOTE: agg and out may alias (in-place) — no __restrict__ on them.
__global__ __launch_bounds__(256) void finalize_kernel(
    const float4* agg, const float4* __restrict__ g,
    const float* __restrict__ dinv, const float* __restrict__ bias,
    float4* out, int do_relu) {
    int t = blockIdx.x * 256 + threadIdx.x;
    if (t >= N * 64) return;
    int v = t >> 6;
    int c = (t & 63) * 4;
    float dv = dinv[v];
    float4 a = agg[t];
    float4 s = g[t];
    float4 r;
    r.x = fmaf(dv, a.x + s.x, bias[c + 0]);
    r.y = fmaf(dv, a.y + s.y, bias[c + 1]);
    r.z = fmaf(dv, a.z + s.z, bias[c + 2]);
    r.w = fmaf(dv, a.w + s.w, bias[c + 3]);
    if (do_relu) {
        r.x = fmaxf(r.x, 0.f);
        r.y = fmaxf(r.y, 0.f);
        r.z = fmaxf(r.z, 0.f);
        r.w = fmaxf(r.w, 0.f);
    }
    out[t] = r;
}

extern "C" void kernel_launch(void* const* d_in, const int* in_sizes, int n_in,
                              void* d_out, int out_size, void* d_ws, size_t ws_size,
                              hipStream_t stream) {
    const float* x  = (const float*)d_in[0];
    const int* edge = (const int*)d_in[1];
    const int* src  = edge;
    const int* dst  = edge + E;
    const float* W1 = (const float*)d_in[2];
    const float* b1 = (const float*)d_in[3];
    const float* W2 = (const float*)d_in[4];
    const float* b2 = (const float*)d_in[5];
    float* out = (float*)d_out;

    // workspace layout (floats): g[N*256] | dinv[N]  -> 51.4 MB total
    // (d_out doubles as the aggregation / x2 buffer so ws stays small)
    float* g    = (float*)d_ws;
    float* dinv = g + (size_t)N * 256;

    const size_t featBytes = (size_t)N * 256 * sizeof(float);

    // normalization
    hipMemsetAsync(dinv, 0, N * sizeof(float), stream);
    deg_kernel<<<(E + 255) / 256, 256, 0, stream>>>(dst, dinv);
    dinv_kernel<<<(N + 255) / 256, 256, 0, stream>>>(dinv);

    // ---- layer 1 ----  g1 = dinv*(x@W1) in ws; aggregate in d_out; x2 in d_out
    gemm_scale_kernel<128><<<dim3((N + 63) / 64, 4), 256, 0, stream>>>(x, W1, dinv, g);
    hipMemsetAsync(out, 0, featBytes, stream);
    scatter_kernel<<<(E * 64) / 256, 256, 0, stream>>>(src, dst, (const float4*)g,
                                                       (float4*)out);
    finalize_kernel<<<(N * 64) / 256 + 1, 256, 0, stream>>>(
        (const float4*)out, (const float4*)g, dinv, b1, (float4*)out, 1);

    // ---- layer 2 ----  g2 = dinv*(x2@W2) in ws (x2 read from d_out first);
    //                    then aggregate + finalize in d_out
    gemm_scale_kernel<256><<<dim3((N + 63) / 64, 4), 256, 0, stream>>>(out, W2, dinv, g);
    hipMemsetAsync(out, 0, featBytes, stream);
    scatter_kernel<<<(E * 64) / 256, 256, 0, stream>>>(src, dst, (const float4*)g,
                                                       (float4*)out);
    finalize_kernel<<<(N * 64) / 256 + 1, 256, 0, stream>>>(
        (const float4*)out, (const float4*)g, dinv, b2, (float4*)out, 0);
}

// Round 3
// 661.660 us; speedup vs baseline: 8.5520x; 8.5520x over previous
//
#include <hip/hip_runtime.h>

constexpr int N = 50000;    // nodes
constexpr int E = 800000;   // edges
constexpr int CHUNK = (N + 255) / 256;   // per-thread span in the scan (196)

// ---------------- int degree histogram (in-degree by dst) ----------------
__global__ __launch_bounds__(256) void deg_kernel(const int* __restrict__ dst,
                                                  int* __restrict__ degI) {
    int e = blockIdx.x * 256 + threadIdx.x;
    if (e < E) atomicAdd(&degI[dst[e]], 1);
}

__global__ __launch_bounds__(256) void dinv_kernel(const int* __restrict__ degI,
                                                   float* __restrict__ dinv) {
    int v = blockIdx.x * 256 + threadIdx.x;
    if (v < N) dinv[v] = rsqrtf((float)degI[v] + 1.0f);   // +1 = self loop
}

// ---------------- single-block exclusive scan -> rowptr, cursor ----------------
__global__ __launch_bounds__(256) void scan_kernel(const int* __restrict__ degI,
                                                   int* __restrict__ rowptr,
                                                   int* __restrict__ cursor) {
    __shared__ int sums[256];
    int t = threadIdx.x;
    int beg = t * CHUNK;
    int end = min(beg + CHUNK, N);
    int s = 0;
    for (int i = beg; i < end; ++i) s += degI[i];
    sums[t] = s;
    __syncthreads();
    // Hillis-Steele inclusive scan in LDS
    for (int off = 1; off < 256; off <<= 1) {
        int v = sums[t];
        int u = (t >= off) ? sums[t - off] : 0;
        __syncthreads();
        sums[t] = v + u;
        __syncthreads();
    }
    int run = (t == 0) ? 0 : sums[t - 1];   // exclusive prefix for this chunk
    for (int i = beg; i < end; ++i) {
        rowptr[i] = run;
        cursor[i] = run;
        run += degI[i];
    }
    if (t == 255) rowptr[N] = run;          // == E
}

// ---------------- CSR fill: eidx grouped by dst, holding src ----------------
__global__ __launch_bounds__(256) void fill_kernel(const int* __restrict__ src,
                                                   const int* __restrict__ dst,
                                                   int* __restrict__ cursor,
                                                   int* __restrict__ eidx) {
    int e = blockIdx.x * 256 + threadIdx.x;
    if (e >= E) return;
    int d = dst[e];
    int pos = atomicAdd(&cursor[d], 1);
    eidx[pos] = src[e];
}

// ---------------- GEMM with dinv row-scale epilogue ----------------
// out[m, c] = dinv[m] * sum_k A[m,k] * W[k,c];   A: [N,K], W: [K,256], out: [N,256]
template <int K>
__global__ __launch_bounds__(256) void gemm_scale_kernel(
    const float* __restrict__ A, const float* __restrict__ W,
    const float* __restrict__ dinv, float* __restrict__ out) {
    constexpr int BM = 64, BN = 64, BK = 32, CN = 256;
    __shared__ __align__(16) float As[BK][BM + 4];  // stored transposed: As[k][m]
    __shared__ __align__(16) float Bs[BK][BN + 4];

    const int bm = blockIdx.x * BM;
    const int bn = blockIdx.y * BN;
    const int tid = threadIdx.x;
    const int tx = tid & 15;   // output col group
    const int ty = tid >> 4;   // output row group

    float acc[4][4] = {};

    for (int k0 = 0; k0 < K; k0 += BK) {
        {
            int kk = (tid & 7) * 4;
            int r0 = tid >> 3;
#pragma unroll
            for (int rr = 0; rr < 2; ++rr) {
                int r = r0 + rr * 32;
                int m = bm + r;
                float4 v = make_float4(0.f, 0.f, 0.f, 0.f);
                if (m < N) v = *(const float4*)&A[(size_t)m * K + k0 + kk];
                As[kk + 0][r] = v.x;
                As[kk + 1][r] = v.y;
                As[kk + 2][r] = v.z;
                As[kk + 3][r] = v.w;
            }
        }
        {
            int c4 = (tid & 15) * 4;
            int r0 = tid >> 4;
#pragma unroll
            for (int rr = 0; rr < 2; ++rr) {
                int r = r0 + rr * 16;
                float4 v = *(const float4*)&W[(size_t)(k0 + r) * CN + bn + c4];
                *(float4*)&Bs[r][c4] = v;
            }
        }
        __syncthreads();

#pragma unroll
        for (int k = 0; k < BK; ++k) {
            float4 a4 = *(const float4*)&As[k][ty * 4];
            float4 b4 = *(const float4*)&Bs[k][tx * 4];
            float av[4] = {a4.x, a4.y, a4.z, a4.w};
            float bv[4] = {b4.x, b4.y, b4.z, b4.w};
#pragma unroll
            for (int i = 0; i < 4; ++i)
#pragma unroll
                for (int j = 0; j < 4; ++j) acc[i][j] = fmaf(av[i], bv[j], acc[i][j]);
        }
        __syncthreads();
    }

#pragma unroll
    for (int i = 0; i < 4; ++i) {
        int m = bm + ty * 4 + i;
        if (m < N) {
            float dv = dinv[m];
            float4 r;
            r.x = acc[i][0] * dv;
            r.y = acc[i][1] * dv;
            r.z = acc[i][2] * dv;
            r.w = acc[i][3] * dv;
            *(float4*)&out[(size_t)m * CN + bn + tx * 4] = r;
        }
    }
}

// ---------------- fused gather-aggregate + finalize ----------------
// out[v] = [relu]( dinv[v] * (g[v] + sum_{u in nbr(v)} g[u]) + bias )
// one wave per node; lane l owns channels 4l..4l+3
__global__ __launch_bounds__(256) void aggregate_kernel(
    const int* __restrict__ rowptr, const int* __restrict__ eidx,
    const float4* __restrict__ g, const float* __restrict__ dinv,
    const float4* __restrict__ bias, float4* __restrict__ out, int do_relu) {
    int v = blockIdx.x * 4 + (threadIdx.x >> 6);
    if (v >= N) return;
    int lane = threadIdx.x & 63;
    int beg = rowptr[v];
    int end = rowptr[v + 1];

    float4 a = g[(size_t)v * 64 + lane];   // self loop
    float4 acc = make_float4(a.x, a.y, a.z, a.w);

    int i = beg;
    for (; i + 1 < end; i += 2) {          // 2-edge unroll for MLP
        int s0 = eidx[i], s1 = eidx[i + 1];
        float4 t0 = g[(size_t)s0 * 64 + lane];
        float4 t1 = g[(size_t)s1 * 64 + lane];
        acc.x += t0.x + t1.x;
        acc.y += t0.y + t1.y;
        acc.z += t0.z + t1.z;
        acc.w += t0.w + t1.w;
    }
    if (i < end) {
        int s0 = eidx[i];
        float4 t0 = g[(size_t)s0 * 64 + lane];
        acc.x += t0.x;
        acc.y += t0.y;
        acc.z += t0.z;
        acc.w += t0.w;
    }

    float dv = dinv[v];
    float4 b4 = bias[lane];
    float4 r;
    r.x = fmaf(dv, acc.x, b4.x);
    r.y = fmaf(dv, acc.y, b4.y);
    r.z = fmaf(dv, acc.z, b4.z);
    r.w = fmaf(dv, acc.w, b4.w);
    if (do_relu) {
        r.x = fmaxf(r.x, 0.f);
        r.y = fmaxf(r.y, 0.f);
        r.z = fmaxf(r.z, 0.f);
        r.w = fmaxf(r.w, 0.f);
    }
    out[(size_t)v * 64 + lane] = r;
}

extern "C" void kernel_launch(void* const* d_in, const int* in_sizes, int n_in,
                              void* d_out, int out_size, void* d_ws, size_t ws_size,
                              hipStream_t stream) {
    const float* x  = (const float*)d_in[0];
    const int* edge = (const int*)d_in[1];
    const int* src  = edge;
    const int* dst  = edge + E;
    const float* W1 = (const float*)d_in[2];
    const float* b1 = (const float*)d_in[3];
    const float* W2 = (const float*)d_in[4];
    const float* b2 = (const float*)d_in[5];
    float* out = (float*)d_out;

    // workspace layout: g[N*256] f | dinv[N] f | degI[N] i | rowptr[N+1] i |
    //                   cursor[N] i | eidx[E] i   -> ~55.3 MB
    float* g      = (float*)d_ws;
    float* dinv   = g + (size_t)N * 256;
    int*   degI   = (int*)(dinv + N);
    int*   rowptr = degI + N;
    int*   cursor = rowptr + (N + 1);
    int*   eidx   = cursor + N;

    // ---- CSR build + normalization ----
    hipMemsetAsync(degI, 0, N * sizeof(int), stream);
    deg_kernel<<<(E + 255) / 256, 256, 0, stream>>>(dst, degI);
    dinv_kernel<<<(N + 255) / 256, 256, 0, stream>>>(degI, dinv);
    scan_kernel<<<1, 256, 0, stream>>>(degI, rowptr, cursor);
    fill_kernel<<<(E + 255) / 256, 256, 0, stream>>>(src, dst, cursor, eidx);

    // ---- layer 1 ----  g1 = dinv*(x@W1); out = relu(dinv*(agg+g1)+b1)
    gemm_scale_kernel<128><<<dim3((N + 63) / 64, 4), 256, 0, stream>>>(x, W1, dinv, g);
    aggregate_kernel<<<(N + 3) / 4, 256, 0, stream>>>(
        rowptr, eidx, (const float4*)g, dinv, (const float4*)b1, (float4*)out, 1);

    // ---- layer 2 ----  g2 = dinv*(out@W2); out = dinv*(agg+g2)+b2
    gemm_scale_kernel<256><<<dim3((N + 63) / 64, 4), 256, 0, stream>>>(out, W2, dinv, g);
    aggregate_kernel<<<(N + 3) / 4, 256, 0, stream>>>(
        rowptr, eidx, (const float4*)g, dinv, (const float4*)b2, (float4*)out, 0);
}

// Round 4
// 525.559 us; speedup vs baseline: 10.7667x; 1.2590x over previous
//
#include <hip/hip_runtime.h>

constexpr int N = 50000;    // nodes
constexpr int E = 800000;   // edges
constexpr int NPAD = 50048; // padded to 64-row multiple for GEMM A tiles
constexpr int CHUNK = (N + 255) / 256;

typedef _Float16 half8 __attribute__((ext_vector_type(8)));
typedef _Float16 half4v __attribute__((ext_vector_type(4)));
typedef float float4v __attribute__((ext_vector_type(4)));

// ---------------- degree / normalization / CSR ----------------
__global__ __launch_bounds__(256) void deg_kernel(const int* __restrict__ dst,
                                                  int* __restrict__ degI) {
    int e = blockIdx.x * 256 + threadIdx.x;
    if (e < E) atomicAdd(&degI[dst[e]], 1);
}

__global__ __launch_bounds__(256) void dinv_kernel(const int* __restrict__ degI,
                                                   float* __restrict__ dinv) {
    int v = blockIdx.x * 256 + threadIdx.x;
    if (v < N) dinv[v] = rsqrtf((float)degI[v] + 1.0f);   // +1 = self loop
}

__global__ __launch_bounds__(256) void scan_kernel(const int* __restrict__ degI,
                                                   int* __restrict__ rowptr,
                                                   int* __restrict__ cursor) {
    __shared__ int sums[256];
    int t = threadIdx.x;
    int beg = t * CHUNK;
    int end = min(beg + CHUNK, N);
    int s = 0;
    for (int i = beg; i < end; ++i) s += degI[i];
    sums[t] = s;
    __syncthreads();
    for (int off = 1; off < 256; off <<= 1) {
        int v = sums[t];
        int u = (t >= off) ? sums[t - off] : 0;
        __syncthreads();
        sums[t] = v + u;
        __syncthreads();
    }
    int run = (t == 0) ? 0 : sums[t - 1];
    for (int i = beg; i < end; ++i) {
        rowptr[i] = run;
        cursor[i] = run;
        run += degI[i];
    }
    if (t == 255) rowptr[N] = run;   // == E
}

__global__ __launch_bounds__(256) void fill_kernel(const int* __restrict__ src,
                                                   const int* __restrict__ dst,
                                                   int* __restrict__ cursor,
                                                   int* __restrict__ eidx) {
    int e = blockIdx.x * 256 + threadIdx.x;
    if (e >= E) return;
    int d = dst[e];
    int pos = atomicAdd(&cursor[d], 1);
    eidx[pos] = src[e];
}

// ---------------- weight transpose+cast: Wt[n][k] = (f16) W[k][n] ----------------
template <int K>
__global__ __launch_bounds__(256) void wt_kernel(const float* __restrict__ W,
                                                 _Float16* __restrict__ Wt) {
    int idx = blockIdx.x * 256 + threadIdx.x;   // 256*K total
    int k = idx & (K - 1);
    int n = idx >> (K == 128 ? 7 : 8);
    Wt[idx] = (_Float16)W[(size_t)k * 256 + n];
}

// ---------------- prescale: px = dinv[v] * x   (fp32 -> fp16, 128 ch) ----------------
__global__ __launch_bounds__(256) void prescale_kernel(const float4* __restrict__ x,
                                                       const float* __restrict__ dinv,
                                                       half4v* __restrict__ px) {
    int idx = blockIdx.x * 256 + threadIdx.x;   // N*32 float4 units
    if (idx >= N * 32) return;
    float dv = dinv[idx >> 5];
    float4 t = x[idx];
    half4v o;
    o[0] = (_Float16)(t.x * dv);
    o[1] = (_Float16)(t.y * dv);
    o[2] = (_Float16)(t.z * dv);
    o[3] = (_Float16)(t.w * dv);
    px[idx] = o;
}

// ---------------- gather-aggregate (fp16 rows, fp32 accum) ----------------
// q[v] = (f16) dinv[v] * ( f[v] + sum_{u->v} f[u] ),   C4 = channels/4 (32 or 64)
template <int C4>
__global__ __launch_bounds__(256) void aggregate_f16(
    const int* __restrict__ rowptr, const int* __restrict__ eidx,
    const half4v* __restrict__ f, const float* __restrict__ dinv,
    half4v* __restrict__ q) {
    int v = blockIdx.x * (256 / C4) + threadIdx.x / C4;
    if (v >= N) return;
    int lane = threadIdx.x % C4;
    int beg = rowptr[v];
    int end = rowptr[v + 1];

    half4v s = f[(size_t)v * C4 + lane];
    float a0 = (float)s[0], a1 = (float)s[1], a2 = (float)s[2], a3 = (float)s[3];

    int i = beg;
    for (; i + 1 < end; i += 2) {
        int s0 = eidx[i], s1 = eidx[i + 1];
        half4v t0 = f[(size_t)s0 * C4 + lane];
        half4v t1 = f[(size_t)s1 * C4 + lane];
        a0 += (float)t0[0] + (float)t1[0];
        a1 += (float)t0[1] + (float)t1[1];
        a2 += (float)t0[2] + (float)t1[2];
        a3 += (float)t0[3] + (float)t1[3];
    }
    if (i < end) {
        half4v t0 = f[(size_t)eidx[i] * C4 + lane];
        a0 += (float)t0[0];
        a1 += (float)t0[1];
        a2 += (float)t0[2];
        a3 += (float)t0[3];
    }

    float dv = dinv[v];
    half4v o;
    o[0] = (_Float16)(a0 * dv);
    o[1] = (_Float16)(a1 * dv);
    o[2] = (_Float16)(a2 * dv);
    o[3] = (_Float16)(a3 * dv);
    q[(size_t)v * C4 + lane] = o;
}

// ---------------- fp16 MFMA GEMM, no LDS ----------------
// D[m,n] = A[m,:K] . W[:,n];  A row-major [NPAD,K] f16, Wt [256,K] f16 (W transposed)
// FUSE1: out f16 = dinv[row]*relu(D+bias)   else: out f32 = D+bias
// block = 256 (4 waves); wave -> 16 rows x 64 cols; grid = (NPAD/64, 4)
template <int K, bool FUSE1>
__global__ __launch_bounds__(256) void gemm_mfma(
    const _Float16* __restrict__ A, const _Float16* __restrict__ Wt,
    const float* __restrict__ bias, const float* __restrict__ dinv,
    void* __restrict__ outp) {
    int wave = threadIdx.x >> 6;
    int lane = threadIdx.x & 63;
    int m = lane & 15;        // A-row / B-col within 16x16 tile
    int quad = lane >> 4;     // k-block selector (k = quad*8 + j)
    int rbase = blockIdx.x * 64 + wave * 16;
    int cbase = blockIdx.y * 64;

    float4v acc[4] = {};

    const half8* Arow = (const half8*)(A + (size_t)(rbase + m) * K);
#pragma unroll
    for (int k0 = 0; k0 < K; k0 += 32) {
        half8 a = Arow[(k0 >> 3) + quad];
#pragma unroll
        for (int c = 0; c < 4; ++c) {
            const half8* Brow = (const half8*)(Wt + (size_t)(cbase + c * 16 + m) * K);
            half8 b = Brow[(k0 >> 3) + quad];
            acc[c] = __builtin_amdgcn_mfma_f32_16x16x32_f16(a, b, acc[c], 0, 0, 0);
        }
    }

#pragma unroll
    for (int c = 0; c < 4; ++c) {
        int col = cbase + c * 16 + m;
        float bcol = bias[col];
#pragma unroll
        for (int r = 0; r < 4; ++r) {
            int row = rbase + quad * 4 + r;   // C/D: col=lane&15, row=quad*4+reg
            if (row < N) {
                float val = acc[c][r] + bcol;
                if (FUSE1) {
                    val = fmaxf(val, 0.f) * dinv[row];
                    ((_Float16*)outp)[(size_t)row * 256 + col] = (_Float16)val;
                } else {
                    ((float*)outp)[(size_t)row * 256 + col] = val;
                }
            }
        }
    }
}

extern "C" void kernel_launch(void* const* d_in, const int* in_sizes, int n_in,
                              void* d_out, int out_size, void* d_ws, size_t ws_size,
                              hipStream_t stream) {
    const float* x  = (const float*)d_in[0];
    const int* edge = (const int*)d_in[1];
    const int* src  = edge;
    const int* dst  = edge + E;
    const float* W1 = (const float*)d_in[2];
    const float* b1 = (const float*)d_in[3];
    const float* W2 = (const float*)d_in[4];
    const float* b2 = (const float*)d_in[5];
    float* out = (float*)d_out;

    // ws layout (~55.4 MB, same budget as the passing R3 kernel):
    //  bufA f16[NPAD*256] : px (first half) -> h1p
    //  bufB f16[NPAD*256] : q1 (first half) -> q2
    //  dinv f32[N] | degI i[N] | rowptr i[N+1] | cursor i[N] | eidx i[E]
    //  W1t f16[256*128] | W2t f16[256*256]
    _Float16* bufA = (_Float16*)d_ws;
    _Float16* bufB = bufA + (size_t)NPAD * 256;
    float* dinv    = (float*)(bufB + (size_t)NPAD * 256);
    int* degI      = (int*)(dinv + N);
    int* rowptr    = degI + N;
    int* cursor    = rowptr + (N + 1);
    int* eidx      = cursor + N;
    _Float16* W1t  = (_Float16*)(eidx + E);
    _Float16* W2t  = W1t + 256 * 128;

    // ---- CSR + normalization ----
    hipMemsetAsync(degI, 0, N * sizeof(int), stream);
    deg_kernel<<<(E + 255) / 256, 256, 0, stream>>>(dst, degI);
    dinv_kernel<<<(N + 255) / 256, 256, 0, stream>>>(degI, dinv);
    scan_kernel<<<1, 256, 0, stream>>>(degI, rowptr, cursor);
    fill_kernel<<<(E + 255) / 256, 256, 0, stream>>>(src, dst, cursor, eidx);

    // ---- weights to f16 transposed ----
    wt_kernel<128><<<(256 * 128) / 256, 256, 0, stream>>>(W1, W1t);
    wt_kernel<256><<<(256 * 256) / 256, 256, 0, stream>>>(W2, W2t);

    // ---- layer 1:  q1 = Ahat x  (aggregate first!), h1p = dinv*relu(q1@W1+b1) ----
    prescale_kernel<<<(N * 32 + 255) / 256, 256, 0, stream>>>(
        (const float4*)x, dinv, (half4v*)bufA);
    aggregate_f16<32><<<(N + 7) / 8, 256, 0, stream>>>(
        rowptr, eidx, (const half4v*)bufA, dinv, (half4v*)bufB);
    gemm_mfma<128, true><<<dim3(NPAD / 64, 4), 256, 0, stream>>>(
        bufB, W1t, b1, dinv, bufA);

    // ---- layer 2:  q2 = Ahat h1, out = q2@W2 + b2 ----
    aggregate_f16<64><<<(N + 3) / 4, 256, 0, stream>>>(
        rowptr, eidx, (const half4v*)bufA, dinv, (half4v*)bufB);
    gemm_mfma<256, false><<<dim3(NPAD / 64, 4), 256, 0, stream>>>(
        bufB, W2t, b2, dinv, out);
}

// Round 5
// 413.218 us; speedup vs baseline: 13.6938x; 1.2719x over previous
//
#include <hip/hip_runtime.h>

constexpr int N = 50000;    // nodes
constexpr int E = 800000;   // edges
constexpr int NPAD = 50048; // padded to 64-row multiple for GEMM A tiles
constexpr int NB = (N + 255) / 256;   // 196 scan blocks

typedef _Float16 half8 __attribute__((ext_vector_type(8)));
typedef _Float16 half4v __attribute__((ext_vector_type(4)));
typedef float float4v __attribute__((ext_vector_type(4)));

// ---------------- degree / normalization / CSR ----------------
__global__ __launch_bounds__(256) void deg_kernel(const int* __restrict__ dst,
                                                  int* __restrict__ degI) {
    int e = blockIdx.x * 256 + threadIdx.x;
    if (e < E) atomicAdd(&degI[dst[e]], 1);
}

__global__ __launch_bounds__(256) void dinv_kernel(const int* __restrict__ degI,
                                                   float* __restrict__ dinv) {
    int v = blockIdx.x * 256 + threadIdx.x;
    if (v < N) dinv[v] = rsqrtf((float)degI[v] + 1.0f);   // +1 = self loop
}

// ---- 3-phase scan: scan1 (per-block inclusive) -> scan2 (block offsets) -> scan3 ----
__global__ __launch_bounds__(256) void scan1_kernel(const int* __restrict__ degI,
                                                    int* __restrict__ incl,
                                                    int* __restrict__ blockSums) {
    __shared__ int s[256];
    int t = threadIdx.x;
    int i = blockIdx.x * 256 + t;
    int d = (i < N) ? degI[i] : 0;
    s[t] = d;
    __syncthreads();
    for (int off = 1; off < 256; off <<= 1) {
        int v = s[t];
        int u = (t >= off) ? s[t - off] : 0;
        __syncthreads();
        s[t] = v + u;
        __syncthreads();
    }
    if (i < N) incl[i] = s[t];
    if (t == 255) blockSums[blockIdx.x] = s[255];
}

__global__ __launch_bounds__(256) void scan2_kernel(int* __restrict__ blockSums) {
    __shared__ int s[256];
    int t = threadIdx.x;
    int v = (t < NB) ? blockSums[t] : 0;
    s[t] = v;
    __syncthreads();
    for (int off = 1; off < 256; off <<= 1) {
        int a = s[t];
        int u = (t >= off) ? s[t - off] : 0;
        __syncthreads();
        s[t] = a + u;
        __syncthreads();
    }
    if (t < NB) blockSums[t] = s[t] - v;   // exclusive block offset
}

__global__ __launch_bounds__(256) void scan3_kernel(const int* __restrict__ degI,
                                                    const int* __restrict__ incl,
                                                    const int* __restrict__ blockSums,
                                                    int* __restrict__ rowptr,
                                                    int* __restrict__ cursor) {
    int i = blockIdx.x * 256 + threadIdx.x;
    if (i < N) {
        int e = blockSums[blockIdx.x] + incl[i] - degI[i];
        rowptr[i] = e;
        cursor[i] = e;
    }
    if (i == 0) rowptr[N] = E;   // total degree is the edge count
}

__global__ __launch_bounds__(256) void fill_kernel(const int* __restrict__ src,
                                                   const int* __restrict__ dst,
                                                   int* __restrict__ cursor,
                                                   int* __restrict__ eidx) {
    int e = blockIdx.x * 256 + threadIdx.x;
    if (e >= E) return;
    int d = dst[e];
    int pos = atomicAdd(&cursor[d], 1);
    eidx[pos] = src[e];
}

// ---------------- weight transpose+cast: Wt[n][k] = (f16) W[k][n] ----------------
template <int K>
__global__ __launch_bounds__(256) void wt_kernel(const float* __restrict__ W,
                                                 _Float16* __restrict__ Wt) {
    int idx = blockIdx.x * 256 + threadIdx.x;   // 256*K total
    int k = idx & (K - 1);
    int n = idx >> (K == 128 ? 7 : 8);
    Wt[idx] = (_Float16)W[(size_t)k * 256 + n];
}

// ---------------- prescale: px = dinv[v] * x   (fp32 -> fp16, 128 ch) ----------------
__global__ __launch_bounds__(256) void prescale_kernel(const float4* __restrict__ x,
                                                       const float* __restrict__ dinv,
                                                       half4v* __restrict__ px) {
    int idx = blockIdx.x * 256 + threadIdx.x;   // N*32 float4 units
    if (idx >= N * 32) return;
    float dv = dinv[idx >> 5];
    float4 t = x[idx];
    half4v o;
    o[0] = (_Float16)(t.x * dv);
    o[1] = (_Float16)(t.y * dv);
    o[2] = (_Float16)(t.z * dv);
    o[3] = (_Float16)(t.w * dv);
    px[idx] = o;
}

// ---------------- gather-aggregate (fp16 rows, fp32 accum) ----------------
// q[v] = (f16) dinv[v] * ( f[v] + sum_{u->v} f[u] ),   C4 = channels/4 (32 or 64)
template <int C4>
__global__ __launch_bounds__(256) void aggregate_f16(
    const int* __restrict__ rowptr, const int* __restrict__ eidx,
    const half4v* __restrict__ f, const float* __restrict__ dinv,
    half4v* __restrict__ q) {
    int v = blockIdx.x * (256 / C4) + threadIdx.x / C4;
    if (v >= N) return;
    int lane = threadIdx.x % C4;
    int beg = rowptr[v];
    int end = rowptr[v + 1];

    half4v s = f[(size_t)v * C4 + lane];
    float a0 = (float)s[0], a1 = (float)s[1], a2 = (float)s[2], a3 = (float)s[3];

    int i = beg;
    for (; i + 1 < end; i += 2) {
        int s0 = eidx[i], s1 = eidx[i + 1];
        half4v t0 = f[(size_t)s0 * C4 + lane];
        half4v t1 = f[(size_t)s1 * C4 + lane];
        a0 += (float)t0[0] + (float)t1[0];
        a1 += (float)t0[1] + (float)t1[1];
        a2 += (float)t0[2] + (float)t1[2];
        a3 += (float)t0[3] + (float)t1[3];
    }
    if (i < end) {
        half4v t0 = f[(size_t)eidx[i] * C4 + lane];
        a0 += (float)t0[0];
        a1 += (float)t0[1];
        a2 += (float)t0[2];
        a3 += (float)t0[3];
    }

    float dv = dinv[v];
    half4v o;
    o[0] = (_Float16)(a0 * dv);
    o[1] = (_Float16)(a1 * dv);
    o[2] = (_Float16)(a2 * dv);
    o[3] = (_Float16)(a3 * dv);
    q[(size_t)v * C4 + lane] = o;
}

// ---------------- fp16 MFMA GEMM, no LDS ----------------
// D[m,n] = A[m,:K] . W[:,n];  A row-major [NPAD,K] f16, Wt [256,K] f16 (W transposed)
// FUSE1: out f16 = dinv[row]*relu(D+bias)   else: out f32 = D+bias
// block = 256 (4 waves); wave -> 16 rows x 64 cols; grid = (NPAD/64, 4)
template <int K, bool FUSE1>
__global__ __launch_bounds__(256) void gemm_mfma(
    const _Float16* __restrict__ A, const _Float16* __restrict__ Wt,
    const float* __restrict__ bias, const float* __restrict__ dinv,
    void* __restrict__ outp) {
    int wave = threadIdx.x >> 6;
    int lane = threadIdx.x & 63;
    int m = lane & 15;        // A-row / B-col within 16x16 tile
    int quad = lane >> 4;     // k-block selector (k = quad*8 + j)
    int rbase = blockIdx.x * 64 + wave * 16;
    int cbase = blockIdx.y * 64;

    float4v acc[4] = {};

    const half8* Arow = (const half8*)(A + (size_t)(rbase + m) * K);
#pragma unroll
    for (int k0 = 0; k0 < K; k0 += 32) {
        half8 a = Arow[(k0 >> 3) + quad];
#pragma unroll
        for (int c = 0; c < 4; ++c) {
            const half8* Brow = (const half8*)(Wt + (size_t)(cbase + c * 16 + m) * K);
            half8 b = Brow[(k0 >> 3) + quad];
            acc[c] = __builtin_amdgcn_mfma_f32_16x16x32_f16(a, b, acc[c], 0, 0, 0);
        }
    }

#pragma unroll
    for (int c = 0; c < 4; ++c) {
        int col = cbase + c * 16 + m;
        float bcol = bias[col];
#pragma unroll
        for (int r = 0; r < 4; ++r) {
            int row = rbase + quad * 4 + r;   // C/D: col=lane&15, row=quad*4+reg
            if (row < N) {
                float val = acc[c][r] + bcol;
                if (FUSE1) {
                    val = fmaxf(val, 0.f) * dinv[row];
                    ((_Float16*)outp)[(size_t)row * 256 + col] = (_Float16)val;
                } else {
                    ((float*)outp)[(size_t)row * 256 + col] = val;
                }
            }
        }
    }
}

extern "C" void kernel_launch(void* const* d_in, const int* in_sizes, int n_in,
                              void* d_out, int out_size, void* d_ws, size_t ws_size,
                              hipStream_t stream) {
    const float* x  = (const float*)d_in[0];
    const int* edge = (const int*)d_in[1];
    const int* src  = edge;
    const int* dst  = edge + E;
    const float* W1 = (const float*)d_in[2];
    const float* b1 = (const float*)d_in[3];
    const float* W2 = (const float*)d_in[4];
    const float* b2 = (const float*)d_in[5];
    float* out = (float*)d_out;

    // ws layout (~55.4 MB):
    //  bufA f16[NPAD*256] : px -> h1p  |  bufB f16[NPAD*256] : q1 -> q2
    //  dinv f32[N] | degI i[N] | rowptr i[N+1] | cursor i[N] (doubles as scan temp)
    //  eidx i[E] | W1t f16[256*128] | W2t f16[256*256] | blockSums i[256]
    _Float16* bufA = (_Float16*)d_ws;
    _Float16* bufB = bufA + (size_t)NPAD * 256;
    float* dinv    = (float*)(bufB + (size_t)NPAD * 256);
    int* degI      = (int*)(dinv + N);
    int* rowptr    = degI + N;
    int* cursor    = rowptr + (N + 1);
    int* eidx      = cursor + N;
    _Float16* W1t  = (_Float16*)(eidx + E);
    _Float16* W2t  = W1t + 256 * 128;
    int* blockSums = (int*)(W2t + 256 * 256);

    // ---- CSR + normalization ----
    hipMemsetAsync(degI, 0, N * sizeof(int), stream);
    deg_kernel<<<(E + 255) / 256, 256, 0, stream>>>(dst, degI);
    dinv_kernel<<<(N + 255) / 256, 256, 0, stream>>>(degI, dinv);
    scan1_kernel<<<NB, 256, 0, stream>>>(degI, cursor, blockSums);   // cursor = incl temp
    scan2_kernel<<<1, 256, 0, stream>>>(blockSums);
    scan3_kernel<<<NB, 256, 0, stream>>>(degI, cursor, blockSums, rowptr, cursor);
    fill_kernel<<<(E + 255) / 256, 256, 0, stream>>>(src, dst, cursor, eidx);

    // ---- weights to f16 transposed ----
    wt_kernel<128><<<(256 * 128) / 256, 256, 0, stream>>>(W1, W1t);
    wt_kernel<256><<<(256 * 256) / 256, 256, 0, stream>>>(W2, W2t);

    // ---- layer 1:  q1 = Ahat x  (aggregate first), h1p = dinv*relu(q1@W1+b1) ----
    prescale_kernel<<<(N * 32 + 255) / 256, 256, 0, stream>>>(
        (const float4*)x, dinv, (half4v*)bufA);
    aggregate_f16<32><<<(N + 7) / 8, 256, 0, stream>>>(
        rowptr, eidx, (const half4v*)bufA, dinv, (half4v*)bufB);
    gemm_mfma<128, true><<<dim3(NPAD / 64, 4), 256, 0, stream>>>(
        bufB, W1t, b1, dinv, bufA);

    // ---- layer 2:  q2 = Ahat h1, out = q2@W2 + b2 ----
    aggregate_f16<64><<<(N + 3) / 4, 256, 0, stream>>>(
        rowptr, eidx, (const half4v*)bufA, dinv, (half4v*)bufB);
    gemm_mfma<256, false><<<dim3(NPAD / 64, 4), 256, 0, stream>>>(
        bufB, W2t, b2, dinv, out);
}